// Round 2
// baseline (474.387 us; speedup 1.0000x reference)
//
#include <hip/hip_runtime.h>
#include <math.h>

// ---------------------------------------------------------------------------
// Pipeline (all fp32, deterministic):
//  k_init   : threshold table (repeated fp32 add, matches JAX while_loop) + zero hist
//  k_conv1  : conv1+bias+relu+maxpool   -> pool1 [2048][20*12*12]
//  k_conv2  : conv2+bias+relu+maxpool   -> pool2 [2048][800]
//  k_gemm64<1>: H = relu(pool2 @ fc_w + fc_b)        [2048][500]
//  k_rowsq  : sq[i] = sum_k H[i,k]^2
//  k_dist   : dist = sqrt(max(sq_i+sq_j-2*H@H^T,0)) + histogram binning
//  k_pick   : parallel cumulative-count scan -> threshold (first cnt >= 615)
//  k_deg    : dinv[i] = 1/sqrt(1 + deg_i)
//  k_gemm64<0>: HW = H @ gcn_w                        [2048][500]
//  k_gcn    : out = log_softmax(dinv_i*(dinv_i*HW_i + sum_nbr dinv_j*HW_j) + b)
// Workspace: ~55 MB of floats.
// ---------------------------------------------------------------------------

#define NN 2048
#define LL 500

// ws offsets (in floats)
#define O_POOL1 ((size_t)0)                          // 2048*2880
#define O_POOL2 (O_POOL1 + (size_t)2048*2880)        // 2048*800
#define O_H     (O_POOL2 + (size_t)2048*800)         // 2048*500
#define O_HW    (O_H     + (size_t)2048*500)         // 2048*500
#define O_DIST  (O_HW    + (size_t)2048*500)         // 2048*2048
#define O_SQ    (O_DIST  + (size_t)2048*2048)        // 2048
#define O_TBL   (O_SQ    + 2048)                     // 1024
#define O_HIST  (O_TBL   + 1024)                     // 1024 (as unsigned)
#define O_THR   (O_HIST  + 1024)                     // 16
#define O_DINV  (O_THR   + 16)                       // 2048

__device__ __forceinline__ float4 ldg4_tail(const float* p, int rem) {
    // rem = valid floats at p; full float4 when rem >= 4, else zero-padded.
    float4 v;
    if (rem >= 4) v = *(const float4*)p;
    else {
        v.x = (rem > 0) ? p[0] : 0.f;
        v.y = (rem > 1) ? p[1] : 0.f;
        v.z = (rem > 2) ? p[2] : 0.f;
        v.w = (rem > 3) ? p[3] : 0.f;
    }
    return v;
}

__device__ __forceinline__ float4 zero4() { float4 v; v.x = v.y = v.z = v.w = 0.f; return v; }

// ---------------------------------------------------------------------------
__global__ void k_init(float* __restrict__ tbl, unsigned* __restrict__ hist) {
    int t = threadIdx.x;
    if (t == 0) {
        float v = 1.7f;                    // THRESH_INIT
        for (int k = 0; k < 1024; k++) { tbl[k] = v; v += 0.1f; }  // exact repeated fp32 add
    }
    for (int i = t; i < 1024; i += 256) hist[i] = 0u;
}

// ---------------------------------------------------------------------------
// conv1: [n,1,28,28] -> conv5x5 VALID -> +b -> relu -> maxpool2 -> [n,20,12,12]
// 4 images/block, 576 work items / 256 threads (2.25 iters).
__global__ __launch_bounds__(256)
void k_conv1(const float* __restrict__ x, const float* __restrict__ w,
             const float* __restrict__ b, float* __restrict__ out) {
    __shared__ float xin[4 * 784];
    int t = threadIdx.x;
    size_t n0 = (size_t)blockIdx.x * 4;
    {
        const float4* src = (const float4*)(x + n0 * 784);
        float4* dst = (float4*)xin;
        for (int i = t; i < 784; i += 256) dst[i] = src[i];
    }
    __syncthreads();
    for (int o = t; o < 576; o += 256) {
        int img = o / 144, p = o - img * 144, py = p / 12, px = p - py * 12;
        const float* xi = &xin[img * 784 + (2 * py) * 28 + 2 * px];
        float pt[36];
        #pragma unroll
        for (int r = 0; r < 6; r++)
            #pragma unroll
            for (int c = 0; c < 6; c++) pt[r * 6 + c] = xi[r * 28 + c];
        #pragma unroll
        for (int cb = 0; cb < 20; cb += 10) {
            float a0[10], a1[10], a2[10], a3[10];
            #pragma unroll
            for (int c = 0; c < 10; c++) { a0[c] = a1[c] = a2[c] = a3[c] = 0.f; }
            #pragma unroll
            for (int ky = 0; ky < 5; ky++)
                #pragma unroll
                for (int kx = 0; kx < 5; kx++) {
                    float p00 = pt[ky * 6 + kx],       p01 = pt[ky * 6 + kx + 1];
                    float p10 = pt[(ky + 1) * 6 + kx], p11 = pt[(ky + 1) * 6 + kx + 1];
                    #pragma unroll
                    for (int c = 0; c < 10; c++) {
                        float wv = w[(cb + c) * 25 + ky * 5 + kx];
                        a0[c] = fmaf(wv, p00, a0[c]); a1[c] = fmaf(wv, p01, a1[c]);
                        a2[c] = fmaf(wv, p10, a2[c]); a3[c] = fmaf(wv, p11, a3[c]);
                    }
                }
            #pragma unroll
            for (int c = 0; c < 10; c++) {
                float v = fmaxf(fmaxf(a0[c], a1[c]), fmaxf(a2[c], a3[c])) + b[cb + c];
                out[(n0 + img) * 2880 + (size_t)(cb + c) * 144 + p] = fmaxf(v, 0.f);
            }
        }
    }
}

// ---------------------------------------------------------------------------
// conv2: [n,20,12,12] -> conv5x5 VALID (20 in ch) -> +b -> relu -> pool -> [n,50,4,4]
// 4 images/block; lane = (img,pos); wave w owns 13 channels (wave-uniform weight
// index -> scalar loads). Input patch regs reused across 13 channels.
__global__ __launch_bounds__(256)
void k_conv2(const float* __restrict__ in, const float* __restrict__ w,
             const float* __restrict__ b, float* __restrict__ out) {
    __shared__ float s_in[4 * 2888];
    int t = threadIdx.x;
    size_t n0 = (size_t)blockIdx.x * 4;
    for (int img = 0; img < 4; img++) {
        const float4* src = (const float4*)(in + (n0 + img) * 2880);
        float4* dst = (float4*)&s_in[img * 2888];
        for (int i = t; i < 720; i += 256) dst[i] = src[i];
    }
    __syncthreads();
    int lane = t & 63;
    int wv = __builtin_amdgcn_readfirstlane(t >> 6);
    int img = lane >> 4, p = lane & 15, py = p >> 2, px = p & 3;
    int cstart = wv * 13;
    const float* base = &s_in[img * 2888 + (2 * py) * 12 + 2 * px];
    float a0[13], a1[13], a2[13], a3[13];
    #pragma unroll
    for (int c = 0; c < 13; c++) { a0[c] = a1[c] = a2[c] = a3[c] = 0.f; }
    for (int ci = 0; ci < 20; ci++) {
        float pt[36];
        const float* bi = base + ci * 144;
        #pragma unroll
        for (int r = 0; r < 6; r++)
            #pragma unroll
            for (int c = 0; c < 6; c++) pt[r * 6 + c] = bi[r * 12 + c];
        #pragma unroll
        for (int ky = 0; ky < 5; ky++)
            #pragma unroll
            for (int kx = 0; kx < 5; kx++) {
                float p00 = pt[ky * 6 + kx],       p01 = pt[ky * 6 + kx + 1];
                float p10 = pt[(ky + 1) * 6 + kx], p11 = pt[(ky + 1) * 6 + kx + 1];
                #pragma unroll
                for (int cc = 0; cc < 13; cc++) {
                    int c = cstart + cc; int cm = (c < 50) ? c : 49;
                    float wt = w[cm * 500 + ci * 25 + ky * 5 + kx];
                    a0[cc] = fmaf(wt, p00, a0[cc]); a1[cc] = fmaf(wt, p01, a1[cc]);
                    a2[cc] = fmaf(wt, p10, a2[cc]); a3[cc] = fmaf(wt, p11, a3[cc]);
                }
            }
    }
    #pragma unroll
    for (int cc = 0; cc < 13; cc++) {
        int c = cstart + cc;
        if (c < 50) {
            float v = fmaxf(fmaxf(a0[cc], a1[cc]), fmaxf(a2[cc], a3[cc])) + b[c];
            out[(n0 + img) * 800 + c * 16 + p] = fmaxf(v, 0.f);
        }
    }
}

// ---------------------------------------------------------------------------
// 64x64-tile fp32 GEMM, BK=32, 256 threads, 4x4 micro-tile, reg-prefetch
// double buffering (issue global loads for k0+32 before computing k0).
// RELU=1: C = relu(A@B + bias); RELU=0: C = A@B.
// Grid: (ceil(N/64), M/64) -> 256 blocks for M=2048,N=500 (full chip).
template <int RELU>
__global__ __launch_bounds__(256)
void k_gemm64(const float* __restrict__ A, const float* __restrict__ B,
              float* __restrict__ C, int M, int N, int K,
              const float* __restrict__ bias) {
    __shared__ __align__(16) float As[32][68];   // [k][m], +4 pad: store 2-way banks
    __shared__ __align__(16) float Bs[32][68];   // [k][n]
    int t = threadIdx.x;
    int m0 = blockIdx.y * 64, n0 = blockIdx.x * 64;
    int ar = t >> 3, ac = (t & 7) * 4;           // A: rows ar, ar+32; k-cols ac..ac+3
    int br = t >> 4, bc = (t & 15) * 4;          // B: k-rows br, br+16; cols bc..bc+3
    int ty = t >> 4, tx = t & 15;
    float acc[4][4] = {};
    float4 pa0, pa1, pb0, pb1;

#define G64_LOAD(k0) do {                                                      \
        int remk = K - ((k0) + ac);                                            \
        pa0 = ldg4_tail(&A[(size_t)(m0 + ar) * K + (k0) + ac], remk);          \
        pa1 = ldg4_tail(&A[(size_t)(m0 + ar + 32) * K + (k0) + ac], remk);     \
        int remn = N - (n0 + bc);                                              \
        pb0 = ((k0) + br < K)                                                  \
            ? ldg4_tail(&B[(size_t)((k0) + br) * N + n0 + bc], remn) : zero4();\
        pb1 = ((k0) + br + 16 < K)                                             \
            ? ldg4_tail(&B[(size_t)((k0) + br + 16) * N + n0 + bc], remn) : zero4(); \
    } while (0)

#define G64_STORE() do {                                                       \
        As[ac + 0][ar] = pa0.x; As[ac + 1][ar] = pa0.y;                        \
        As[ac + 2][ar] = pa0.z; As[ac + 3][ar] = pa0.w;                        \
        As[ac + 0][ar + 32] = pa1.x; As[ac + 1][ar + 32] = pa1.y;              \
        As[ac + 2][ar + 32] = pa1.z; As[ac + 3][ar + 32] = pa1.w;              \
        *(float4*)&Bs[br][bc] = pb0;                                           \
        *(float4*)&Bs[br + 16][bc] = pb1;                                      \
    } while (0)

    G64_LOAD(0); G64_STORE(); __syncthreads();
    for (int k0 = 0; k0 < K; k0 += 32) {
        bool more = (k0 + 32) < K;
        if (more) G64_LOAD(k0 + 32);
        #pragma unroll
        for (int kk = 0; kk < 32; kk++) {
            float4 a4 = *(const float4*)&As[kk][ty * 4];
            float4 b4 = *(const float4*)&Bs[kk][tx * 4];
            float av[4] = {a4.x, a4.y, a4.z, a4.w};
            float bv[4] = {b4.x, b4.y, b4.z, b4.w};
            #pragma unroll
            for (int i = 0; i < 4; i++)
                #pragma unroll
                for (int j = 0; j < 4; j++) acc[i][j] = fmaf(av[i], bv[j], acc[i][j]);
        }
        __syncthreads();
        if (more) { G64_STORE(); __syncthreads(); }
    }
#undef G64_LOAD
#undef G64_STORE

    #pragma unroll
    for (int i = 0; i < 4; i++) {
        int row = m0 + ty * 4 + i;
        int c0 = n0 + tx * 4;
        if (c0 + 3 < N) {
            float4 vv;
            float* pv = &vv.x;
            #pragma unroll
            for (int j = 0; j < 4; j++) {
                float a = acc[i][j];
                if (RELU) { a += bias[c0 + j]; a = fmaxf(a, 0.f); }
                pv[j] = a;
            }
            *(float4*)&C[(size_t)row * N + c0] = vv;
        } else {
            #pragma unroll
            for (int j = 0; j < 4; j++) {
                if (c0 + j < N) {
                    float a = acc[i][j];
                    if (RELU) { a += bias[c0 + j]; a = fmaxf(a, 0.f); }
                    C[(size_t)row * N + c0 + j] = a;
                }
            }
        }
    }
}

// ---------------------------------------------------------------------------
__global__ __launch_bounds__(256)
void k_rowsq(const float* __restrict__ H, float* __restrict__ sq) {
    int t = threadIdx.x, lane = t & 63, wv = t >> 6;
    int row = blockIdx.x * 4 + wv;
    const float* h = &H[(size_t)row * LL];
    float s = 0.f;
    for (int j = lane; j < LL; j += 64) { float v = h[j]; s = fmaf(v, v, s); }
    #pragma unroll
    for (int o = 32; o > 0; o >>= 1) s += __shfl_down(s, o, 64);
    if (lane == 0) sq[row] = s;
}

// ---------------------------------------------------------------------------
// dist GEMM: 128x128 tile, BK=16, 8x8 micro-tile, reg-prefetch dbuf.
// dist = sqrt(max(sq_i + sq_j - 2*H@H^T, 0)); histogram per-block then global.
// Grid (16,16) = 256 blocks.
__global__ __launch_bounds__(256)
void k_dist(const float* __restrict__ Hm, float* __restrict__ C,
            const float* __restrict__ sq, const float* __restrict__ tbl_g,
            unsigned* __restrict__ hist_g) {
    __shared__ __align__(16) float As[16][128];
    __shared__ __align__(16) float Bs[16][128];
    __shared__ float tbl_s[1024];
    __shared__ unsigned hist_s[1024];
    const int K = LL, N = NN;
    int t = threadIdx.x;
    int m0 = blockIdx.y * 128, n0 = blockIdx.x * 128;
    for (int i = t; i < 1024; i += 256) { tbl_s[i] = tbl_g[i]; hist_s[i] = 0u; }
    float acc[8][8] = {};
    int lr = t >> 2, lc = (t & 3) * 4;
    int ty = t >> 4, tx = t & 15;
    float4 pa0, pa1, pb0, pb1;

#define DIST_LOAD(k0) do {                                                     \
        int rem = K - ((k0) + lc);                                             \
        pa0 = ldg4_tail(&Hm[(size_t)(m0 + lr) * K + (k0) + lc], rem);          \
        pa1 = ldg4_tail(&Hm[(size_t)(m0 + lr + 64) * K + (k0) + lc], rem);     \
        pb0 = ldg4_tail(&Hm[(size_t)(n0 + lr) * K + (k0) + lc], rem);          \
        pb1 = ldg4_tail(&Hm[(size_t)(n0 + lr + 64) * K + (k0) + lc], rem);     \
    } while (0)

#define DIST_STORE() do {                                                      \
        As[lc + 0][lr] = pa0.x; As[lc + 1][lr] = pa0.y;                        \
        As[lc + 2][lr] = pa0.z; As[lc + 3][lr] = pa0.w;                        \
        As[lc + 0][lr + 64] = pa1.x; As[lc + 1][lr + 64] = pa1.y;              \
        As[lc + 2][lr + 64] = pa1.z; As[lc + 3][lr + 64] = pa1.w;              \
        Bs[lc + 0][lr] = pb0.x; Bs[lc + 1][lr] = pb0.y;                        \
        Bs[lc + 2][lr] = pb0.z; Bs[lc + 3][lr] = pb0.w;                        \
        Bs[lc + 0][lr + 64] = pb1.x; Bs[lc + 1][lr + 64] = pb1.y;              \
        Bs[lc + 2][lr + 64] = pb1.z; Bs[lc + 3][lr + 64] = pb1.w;              \
    } while (0)

    DIST_LOAD(0); DIST_STORE(); __syncthreads();
    for (int k0 = 0; k0 < K; k0 += 16) {
        bool more = (k0 + 16) < K;
        if (more) DIST_LOAD(k0 + 16);
        #pragma unroll
        for (int kk = 0; kk < 16; kk++) {
            float4 A0 = *(const float4*)&As[kk][ty * 8];
            float4 A1 = *(const float4*)&As[kk][ty * 8 + 4];
            float4 B0 = *(const float4*)&Bs[kk][tx * 4];
            float4 B1 = *(const float4*)&Bs[kk][64 + tx * 4];
            float av[8] = {A0.x, A0.y, A0.z, A0.w, A1.x, A1.y, A1.z, A1.w};
            float bv[8] = {B0.x, B0.y, B0.z, B0.w, B1.x, B1.y, B1.z, B1.w};
            #pragma unroll
            for (int i = 0; i < 8; i++)
                #pragma unroll
                for (int j = 0; j < 8; j++) acc[i][j] = fmaf(av[i], bv[j], acc[i][j]);
        }
        __syncthreads();
        if (more) { DIST_STORE(); __syncthreads(); }
    }
#undef DIST_LOAD
#undef DIST_STORE

    #pragma unroll
    for (int ii = 0; ii < 8; ii++) {
        int i = m0 + ty * 8 + ii;
        float sqi = sq[i];
        #pragma unroll
        for (int g = 0; g < 2; g++) {
            int c0 = n0 + g * 64 + tx * 4;
            float dd[4];
            #pragma unroll
            for (int j = 0; j < 4; j++) {
                int col = c0 + j;
                float d2 = sqi + sq[col] - 2.0f * acc[ii][g * 4 + j];
                float d = sqrtf(fmaxf(d2, 0.f));
                dd[j] = d;
                if (col != i) {
                    int bb = (int)ceilf((d - 1.7f) * 10.0f);
                    bb = bb < 0 ? 0 : (bb > 1023 ? 1023 : bb);
                    while (bb > 0 && d < tbl_s[bb - 1]) --bb;
                    while (bb < 1023 && d >= tbl_s[bb]) ++bb;
                    if (d < tbl_s[bb]) atomicAdd(&hist_s[bb], 1u);
                }
            }
            float4 dv; dv.x = dd[0]; dv.y = dd[1]; dv.z = dd[2]; dv.w = dd[3];
            *(float4*)&C[(size_t)i * N + c0] = dv;
        }
    }
    __syncthreads();
    for (int idx = t; idx < 1024; idx += 256)
        if (hist_s[idx]) atomicAdd(&hist_g[idx], hist_s[idx]);
}

// ---------------------------------------------------------------------------
// Parallel threshold pick: prefix-scan the 1024-bin histogram, first cumulative
// count >= 615 (= first integer >= f32(0.3*2048)) selects tbl[k].
__global__ __launch_bounds__(256)
void k_pick(const unsigned* __restrict__ hist, const float* __restrict__ tbl,
            float* __restrict__ thrbuf) {
    __shared__ unsigned ps[256];
    __shared__ int sel;
    int t = threadIdx.x;
    if (t == 0) sel = 1023;
    unsigned v0 = hist[4 * t], v1 = hist[4 * t + 1],
             v2 = hist[4 * t + 2], v3 = hist[4 * t + 3];
    unsigned s = v0 + v1 + v2 + v3;
    ps[t] = s;
    __syncthreads();
    for (int o = 1; o < 256; o <<= 1) {
        unsigned add = (t >= o) ? ps[t - o] : 0u;
        __syncthreads();
        ps[t] += add;
        __syncthreads();
    }
    unsigned c = ps[t] - s;   // exclusive prefix
    int f = -1;
    c += v0; if (c >= 615u) f = 4 * t;
    else { c += v1; if (c >= 615u) f = 4 * t + 1;
    else { c += v2; if (c >= 615u) f = 4 * t + 2;
    else { c += v3; if (c >= 615u) f = 4 * t + 3; } } }
    if (f >= 0) atomicMin(&sel, f);
    __syncthreads();
    if (t == 0) thrbuf[0] = tbl[sel];
}

// ---------------------------------------------------------------------------
__global__ __launch_bounds__(256)
void k_deg(const float* __restrict__ dist, const float* __restrict__ thrbuf,
           float* __restrict__ dinv) {
    int t = threadIdx.x, lane = t & 63, wv = t >> 6;
    int row = blockIdx.x * 4 + wv;
    float thr = thrbuf[0];
    const float4* dr4 = (const float4*)&dist[(size_t)row * NN];
    int cnt = 0;
    #pragma unroll
    for (int bq = 0; bq < 8; bq++) {
        int i4 = bq * 64 + lane;
        float4 v = dr4[i4];
        int j = i4 * 4;
        cnt += (v.x < thr && j + 0 != row) ? 1 : 0;
        cnt += (v.y < thr && j + 1 != row) ? 1 : 0;
        cnt += (v.z < thr && j + 2 != row) ? 1 : 0;
        cnt += (v.w < thr && j + 3 != row) ? 1 : 0;
    }
    #pragma unroll
    for (int o = 32; o > 0; o >>= 1) cnt += __shfl_down(cnt, o, 64);
    if (lane == 0) dinv[row] = 1.0f / sqrtf((float)(cnt + 1));
}

// ---------------------------------------------------------------------------
// Per-row sparse GCN aggregate + bias + log_softmax. Block = one row.
// Deterministic neighbor compaction (scan-ordered, ascending j).
__global__ __launch_bounds__(256)
void k_gcn(const float* __restrict__ dist, const float* __restrict__ thrbuf,
           const float* __restrict__ dinv, const float* __restrict__ HW,
           const float* __restrict__ bias, float* __restrict__ outp) {
    __shared__ int nbr[2048];
    __shared__ float ndv[2048];
    __shared__ unsigned cnts[256];
    __shared__ float red[16];
    int t = threadIdx.x, lane = t & 63, wv = t >> 6;
    int i = blockIdx.x;
    float thr = thrbuf[0];
    const float* dr = &dist[(size_t)i * NN];
    float4 q0 = *(const float4*)&dr[t * 8];
    float4 q1 = *(const float4*)&dr[t * 8 + 4];
    float dv[8] = {q0.x, q0.y, q0.z, q0.w, q1.x, q1.y, q1.z, q1.w};
    unsigned lc = 0;
    #pragma unroll
    for (int q = 0; q < 8; q++) lc += (dv[q] < thr && (t * 8 + q) != i) ? 1u : 0u;
    cnts[t] = lc;
    __syncthreads();
    for (int o = 1; o < 256; o <<= 1) {
        unsigned add = (t >= o) ? cnts[t - o] : 0u;
        __syncthreads();
        cnts[t] += add;
        __syncthreads();
    }
    unsigned pos = cnts[t] - lc;
    int nn = (int)cnts[255];
    #pragma unroll
    for (int q = 0; q < 8; q++) {
        int j = t * 8 + q;
        if (dv[q] < thr && j != i) { nbr[pos] = j; ndv[pos] = dinv[j]; pos++; }
    }
    __syncthreads();
    float di = dinv[i];
    float v0, v1 = -1e30f, mx;
    {
        int d = t;
        float s = di * HW[(size_t)i * LL + d];
        for (int m = 0; m < nn; m++) s += ndv[m] * HW[(size_t)nbr[m] * LL + d];
        v0 = di * s + bias[d];
        mx = v0;
    }
    if (t + 256 < LL) {
        int d = t + 256;
        float s = di * HW[(size_t)i * LL + d];
        for (int m = 0; m < nn; m++) s += ndv[m] * HW[(size_t)nbr[m] * LL + d];
        v1 = di * s + bias[d];
        mx = fmaxf(mx, v1);
    }
    #pragma unroll
    for (int o = 32; o > 0; o >>= 1) mx = fmaxf(mx, __shfl_down(mx, o, 64));
    if (lane == 0) red[wv] = mx;
    __syncthreads();
    mx = fmaxf(fmaxf(red[0], red[1]), fmaxf(red[2], red[3]));
    float es = expf(v0 - mx) + ((t + 256 < LL) ? expf(v1 - mx) : 0.f);
    #pragma unroll
    for (int o = 32; o > 0; o >>= 1) es += __shfl_down(es, o, 64);
    if (lane == 0) red[8 + wv] = es;
    __syncthreads();
    float lse = logf(red[8] + red[9] + red[10] + red[11]);
    outp[(size_t)i * LL + t] = v0 - mx - lse;
    if (t + 256 < LL) outp[(size_t)i * LL + t + 256] = v1 - mx - lse;
}

// ---------------------------------------------------------------------------
extern "C" void kernel_launch(void* const* d_in, const int* in_sizes, int n_in,
                              void* d_out, int out_size, void* d_ws, size_t ws_size,
                              hipStream_t stream) {
    (void)in_sizes; (void)n_in; (void)out_size; (void)ws_size;
    const float* x   = (const float*)d_in[0];
    const float* c1w = (const float*)d_in[1];
    const float* c1b = (const float*)d_in[2];
    const float* c2w = (const float*)d_in[3];
    const float* c2b = (const float*)d_in[4];
    const float* fcw = (const float*)d_in[5];
    const float* fcb = (const float*)d_in[6];
    const float* gw  = (const float*)d_in[7];
    const float* gb  = (const float*)d_in[8];

    float* ws = (float*)d_ws;
    float* pool1 = ws + O_POOL1;
    float* pool2 = ws + O_POOL2;
    float* H     = ws + O_H;
    float* HWp   = ws + O_HW;
    float* distm = ws + O_DIST;
    float* sqv   = ws + O_SQ;
    float* tbl   = ws + O_TBL;
    unsigned* hist = (unsigned*)(ws + O_HIST);
    float* thr   = ws + O_THR;
    float* dinv  = ws + O_DINV;

    k_init<<<1, 256, 0, stream>>>(tbl, hist);
    k_conv1<<<512, 256, 0, stream>>>(x, c1w, c1b, pool1);
    k_conv2<<<512, 256, 0, stream>>>(pool1, c2w, c2b, pool2);
    k_gemm64<1><<<dim3(8, 32), 256, 0, stream>>>(pool2, fcw, H, 2048, 500, 800, fcb);
    k_rowsq<<<512, 256, 0, stream>>>(H, sqv);
    k_dist<<<dim3(16, 16), 256, 0, stream>>>(H, distm, sqv, tbl, hist);
    k_pick<<<1, 256, 0, stream>>>(hist, tbl, thr);
    k_deg<<<512, 256, 0, stream>>>(distm, thr, dinv);
    k_gemm64<0><<<dim3(8, 32), 256, 0, stream>>>(H, gw, HWp, 2048, 500, 500, nullptr);
    k_gcn<<<2048, 256, 0, stream>>>(distm, thr, dinv, HWp, gb, (float*)d_out);
}

// Round 6
// 370.705 us; speedup vs baseline: 1.2797x; 1.2797x over previous
//
#include <hip/hip_runtime.h>
#include <math.h>

// ---------------------------------------------------------------------------
// Pipeline (all fp32, deterministic):
//  k_init   : threshold table (repeated fp32 add, matches JAX while_loop) + zero hist
//  k_conv1  : conv1+bias+relu+maxpool   -> pool1 [2048][20*12*12]
//  k_conv2  : conv2+bias+relu+maxpool   -> pool2 [2048][800]
//  k_gemm<1>: H = relu(pool2 @ fc_w + fc_b)          [2048][500]
//  k_rowsq  : sq[i] = sum_k H[i,k]^2
//  k_dist   : dist = sqrt(max(sq_i+sq_j-2*H@H^T,0)) + histogram binning
//  k_pick   : parallel cumulative-count scan -> threshold (first cnt >= 615)
//  k_deg    : dinv[i] = 1/sqrt(1 + deg_i)
//  k_gemm<0>: HW = H @ gcn_w                          [2048][500]
//  k_gcn    : out = log_softmax(dinv_i*(dinv_i*HW_i + sum_nbr dinv_j*HW_j) + b)
// ---------------------------------------------------------------------------

#define NN 2048
#define LL 500
#define NBIN 512

// Pin a float in a VGPR: stops the compiler from sinking/rematerializing the
// LDS load inside inner loops (R2: VGPR=68 proved it rematerialized -> 40% VALU).
#define KEEP(x) asm volatile("" : "+v"(x))

// ws offsets (in floats)
#define O_POOL1 ((size_t)0)                          // 2048*2880
#define O_POOL2 (O_POOL1 + (size_t)2048*2880)        // 2048*800
#define O_H     (O_POOL2 + (size_t)2048*800)         // 2048*500
#define O_HW    (O_H     + (size_t)2048*500)         // 2048*500
#define O_DIST  (O_HW    + (size_t)2048*500)         // 2048*2048
#define O_SQ    (O_DIST  + (size_t)2048*2048)        // 2048
#define O_TBL   (O_SQ    + 2048)                     // NBIN
#define O_HIST  (O_TBL   + NBIN)                     // NBIN (as unsigned)
#define O_THR   (O_HIST  + NBIN)                     // 16
#define O_DINV  (O_THR   + 16)                       // 2048

__device__ __forceinline__ float4 ldg4_tail(const float* p, int rem) {
    float4 v;
    if (rem >= 4) v = *(const float4*)p;
    else {
        v.x = (rem > 0) ? p[0] : 0.f;
        v.y = (rem > 1) ? p[1] : 0.f;
        v.z = (rem > 2) ? p[2] : 0.f;
        v.w = (rem > 3) ? p[3] : 0.f;
    }
    return v;
}

__device__ __forceinline__ float4 zero4() { float4 v; v.x = v.y = v.z = v.w = 0.f; return v; }

// ---------------------------------------------------------------------------
__global__ void k_init(float* __restrict__ tbl, unsigned* __restrict__ hist) {
    int t = threadIdx.x;
    if (t == 0) {
        float v = 1.7f;                    // THRESH_INIT
        for (int k = 0; k < NBIN; k++) { tbl[k] = v; v += 0.1f; }  // exact repeated fp32 add
    }
    for (int i = t; i < NBIN; i += 256) hist[i] = 0u;
}

// ---------------------------------------------------------------------------
// conv1: [n,1,28,28] -> conv5x5 VALID -> +b -> relu -> maxpool2 -> [n,20,12,12]
// 4 images/block, 512 threads (8 waves), grid 512 -> 16 waves/CU.
__global__ __launch_bounds__(512)
void k_conv1(const float* __restrict__ x, const float* __restrict__ w,
             const float* __restrict__ b, float* __restrict__ out) {
    __shared__ float xin[4 * 784];
    int t = threadIdx.x;
    size_t n0 = (size_t)blockIdx.x * 4;
    {
        const float4* src = (const float4*)(x + n0 * 784);
        float4* dst = (float4*)xin;
        for (int i = t; i < 784; i += 512) dst[i] = src[i];
    }
    __syncthreads();
    for (int o = t; o < 576; o += 512) {
        int img = o / 144, p = o - img * 144, py = p / 12, px = p - py * 12;
        const float* xi = &xin[img * 784 + (2 * py) * 28 + 2 * px];
        float pt[36];
        #pragma unroll
        for (int r = 0; r < 6; r++)
            #pragma unroll
            for (int c = 0; c < 6; c++) { pt[r * 6 + c] = xi[r * 28 + c]; KEEP(pt[r * 6 + c]); }
        #pragma unroll
        for (int cb = 0; cb < 20; cb += 10) {
            float a0[10], a1[10], a2[10], a3[10];
            #pragma unroll
            for (int c = 0; c < 10; c++) { a0[c] = a1[c] = a2[c] = a3[c] = 0.f; }
            #pragma unroll
            for (int ky = 0; ky < 5; ky++)
                #pragma unroll
                for (int kx = 0; kx < 5; kx++) {
                    float p00 = pt[ky * 6 + kx],       p01 = pt[ky * 6 + kx + 1];
                    float p10 = pt[(ky + 1) * 6 + kx], p11 = pt[(ky + 1) * 6 + kx + 1];
                    #pragma unroll
                    for (int c = 0; c < 10; c++) {
                        float wv = w[(cb + c) * 25 + ky * 5 + kx];
                        a0[c] = fmaf(wv, p00, a0[c]); a1[c] = fmaf(wv, p01, a1[c]);
                        a2[c] = fmaf(wv, p10, a2[c]); a3[c] = fmaf(wv, p11, a3[c]);
                    }
                }
            #pragma unroll
            for (int c = 0; c < 10; c++) {
                float v = fmaxf(fmaxf(a0[c], a1[c]), fmaxf(a2[c], a3[c])) + b[cb + c];
                out[(n0 + img) * 2880 + (size_t)(cb + c) * 144 + p] = fmaxf(v, 0.f);
            }
        }
    }
}

// ---------------------------------------------------------------------------
// conv2: [n,20,12,12] -> conv5x5 VALID (20 in ch) -> +b -> relu -> pool -> [n,50,4,4]
// 4 images/block, 512 threads (8 waves), 7 channels/wave (wave-uniform weight
// index -> scalar loads). 28 acc + 36 pt regs; KEEP pins the patch in VGPRs.
__global__ __launch_bounds__(512)
void k_conv2(const float* __restrict__ in, const float* __restrict__ w,
             const float* __restrict__ b, float* __restrict__ out) {
    __shared__ float s_in[4 * 2888];
    int t = threadIdx.x;
    size_t n0 = (size_t)blockIdx.x * 4;
    for (int img = 0; img < 4; img++) {
        const float4* src = (const float4*)(in + (n0 + img) * 2880);
        float4* dst = (float4*)&s_in[img * 2888];
        for (int i = t; i < 720; i += 512) dst[i] = src[i];
    }
    __syncthreads();
    int lane = t & 63;
    int wv = __builtin_amdgcn_readfirstlane(t >> 6);   // 0..7
    int img = lane >> 4, p = lane & 15, py = p >> 2, px = p & 3;
    int cstart = wv * 7;                                // 0..49 (+clamped tail)
    const float* base = &s_in[img * 2888 + (2 * py) * 12 + 2 * px];
    float a0[7], a1[7], a2[7], a3[7];
    #pragma unroll
    for (int c = 0; c < 7; c++) { a0[c] = a1[c] = a2[c] = a3[c] = 0.f; }
    for (int ci = 0; ci < 20; ci++) {
        float pt[36];
        const float* bi = base + ci * 144;
        #pragma unroll
        for (int r = 0; r < 6; r++)
            #pragma unroll
            for (int c = 0; c < 6; c++) { pt[r * 6 + c] = bi[r * 12 + c]; KEEP(pt[r * 6 + c]); }
        #pragma unroll
        for (int ky = 0; ky < 5; ky++)
            #pragma unroll
            for (int kx = 0; kx < 5; kx++) {
                float p00 = pt[ky * 6 + kx],       p01 = pt[ky * 6 + kx + 1];
                float p10 = pt[(ky + 1) * 6 + kx], p11 = pt[(ky + 1) * 6 + kx + 1];
                #pragma unroll
                for (int cc = 0; cc < 7; cc++) {
                    int c = cstart + cc; int cm = (c < 50) ? c : 49;
                    float wt = w[cm * 500 + ci * 25 + ky * 5 + kx];
                    a0[cc] = fmaf(wt, p00, a0[cc]); a1[cc] = fmaf(wt, p01, a1[cc]);
                    a2[cc] = fmaf(wt, p10, a2[cc]); a3[cc] = fmaf(wt, p11, a3[cc]);
                }
            }
    }
    #pragma unroll
    for (int cc = 0; cc < 7; cc++) {
        int c = cstart + cc;
        if (c < 50) {
            float v = fmaxf(fmaxf(a0[cc], a1[cc]), fmaxf(a2[cc], a3[cc])) + b[c];
            out[(n0 + img) * 800 + c * 16 + p] = fmaxf(v, 0.f);
        }
    }
}

// ---------------------------------------------------------------------------
// 64x32-tile fp32 GEMM, BK=32, 256 threads, 4x2 micro-tile, reg-prefetch dbuf.
// Grid (ceil(N/32), M/64) = (16,32) = 512 blocks -> 2 blocks/CU, 2 waves/SIMD
// (R2/R3 64x64 version was 256 blocks = 1 wave/SIMD -> 40% VALU).
// RELU=1: C = relu(A@B + bias); RELU=0: C = A@B.
template <int RELU>
__global__ __launch_bounds__(256)
void k_gemm(const float* __restrict__ A, const float* __restrict__ B,
            float* __restrict__ C, int M, int N, int K,
            const float* __restrict__ bias) {
    __shared__ __align__(16) float As[32][68];   // [k][m] (64 rows)
    __shared__ __align__(16) float Bs[32][36];   // [k][n] (32 cols)
    int t = threadIdx.x;
    int m0 = blockIdx.y * 64, n0 = blockIdx.x * 32;
    int ar = t >> 3, ac = (t & 7) * 4;           // A loader: rows ar, ar+32
    int br = t >> 3, bc = (t & 7) * 4;           // B loader: k-row br, cols bc..+3
    int ty = t >> 4, tx = t & 15;                // micro: rows ty*4..+3, cols tx*2..+1
    float acc[4][2] = {};
    float4 pa0, pa1, pb0;

#define GM_LOAD(k0) do {                                                       \
        int remk = K - ((k0) + ac);                                            \
        pa0 = ldg4_tail(&A[(size_t)(m0 + ar) * K + (k0) + ac], remk);          \
        pa1 = ldg4_tail(&A[(size_t)(m0 + ar + 32) * K + (k0) + ac], remk);     \
        pb0 = ((k0) + br < K)                                                  \
            ? ldg4_tail(&B[(size_t)((k0) + br) * N + n0 + bc], N - (n0 + bc))  \
            : zero4();                                                         \
    } while (0)

#define GM_STORE() do {                                                       \
        As[ac + 0][ar] = pa0.x; As[ac + 1][ar] = pa0.y;                        \
        As[ac + 2][ar] = pa0.z; As[ac + 3][ar] = pa0.w;                        \
        As[ac + 0][ar + 32] = pa1.x; As[ac + 1][ar + 32] = pa1.y;              \
        As[ac + 2][ar + 32] = pa1.z; As[ac + 3][ar + 32] = pa1.w;              \
        *(float4*)&Bs[br][bc] = pb0;                                           \
    } while (0)

    GM_LOAD(0); GM_STORE(); __syncthreads();
    for (int k0 = 0; k0 < K; k0 += 32) {
        bool more = (k0 + 32) < K;
        if (more) GM_LOAD(k0 + 32);
        #pragma unroll
        for (int kk = 0; kk < 32; kk++) {
            float4 a4 = *(const float4*)&As[kk][ty * 4];
            float2 b2 = *(const float2*)&Bs[kk][tx * 2];
            float av[4] = {a4.x, a4.y, a4.z, a4.w};
            float bv[2] = {b2.x, b2.y};
            #pragma unroll
            for (int i = 0; i < 4; i++)
                #pragma unroll
                for (int j = 0; j < 2; j++) acc[i][j] = fmaf(av[i], bv[j], acc[i][j]);
        }
        __syncthreads();
        if (more) { GM_STORE(); __syncthreads(); }
    }
#undef GM_LOAD
#undef GM_STORE

    #pragma unroll
    for (int i = 0; i < 4; i++) {
        int row = m0 + ty * 4 + i;
        int c0 = n0 + tx * 2;
        #pragma unroll
        for (int j = 0; j < 2; j++) {
            if (c0 + j < N) {
                float a = acc[i][j];
                if (RELU) { a += bias[c0 + j]; a = fmaxf(a, 0.f); }
                C[(size_t)row * N + c0 + j] = a;
            }
        }
    }
}

// ---------------------------------------------------------------------------
__global__ __launch_bounds__(256)
void k_rowsq(const float* __restrict__ H, float* __restrict__ sq) {
    int t = threadIdx.x, lane = t & 63, wv = t >> 6;
    int row = blockIdx.x * 4 + wv;
    const float* h = &H[(size_t)row * LL];
    float s = 0.f;
    for (int j = lane; j < LL; j += 64) { float v = h[j]; s = fmaf(v, v, s); }
    #pragma unroll
    for (int o = 32; o > 0; o >>= 1) s += __shfl_down(s, o, 64);
    if (lane == 0) sq[row] = s;
}

// ---------------------------------------------------------------------------
// dist GEMM: tile 128(m)x64(n), BK=32, 8x4 micro, 256 threads, reg-prefetch dbuf.
// Grid (32,16) = 512 blocks -> 2 blocks/CU, 2 waves/SIMD.
// dist = sqrt(max(sq_i + sq_j - 2*H@H^T, 0)); per-block histogram then global.
__global__ __launch_bounds__(256)
void k_dist(const float* __restrict__ Hm, float* __restrict__ C,
            const float* __restrict__ sq, const float* __restrict__ tbl_g,
            unsigned* __restrict__ hist_g) {
    __shared__ __align__(16) float As[32][132];  // [k][m]
    __shared__ __align__(16) float Bs[32][68];   // [k][n]
    __shared__ float tbl_s[NBIN];
    __shared__ unsigned hist_s[NBIN];
    const int K = LL, N = NN;
    int t = threadIdx.x;
    int m0 = blockIdx.y * 128, n0 = blockIdx.x * 64;
    for (int i = t; i < NBIN; i += 256) { tbl_s[i] = tbl_g[i]; hist_s[i] = 0u; }
    float acc[8][4] = {};
    int alr = t >> 3, alc = (t & 7) * 4;   // A loader: rows alr+32h, k-cols alc..+3
    int bnr = t >> 2, bkc = (t & 3) * 4;   // B loader: row bnr, k-cols bkc, bkc+16
    int ty = t >> 4, tx = t & 15;
    float4 pa0, pa1, pa2, pa3, pb0, pb1;

#define DIST_LOAD(k0) do {                                                     \
        int rem = K - ((k0) + alc);                                            \
        pa0 = ldg4_tail(&Hm[(size_t)(m0 + alr) * K + (k0) + alc], rem);        \
        pa1 = ldg4_tail(&Hm[(size_t)(m0 + alr + 32) * K + (k0) + alc], rem);   \
        pa2 = ldg4_tail(&Hm[(size_t)(m0 + alr + 64) * K + (k0) + alc], rem);   \
        pa3 = ldg4_tail(&Hm[(size_t)(m0 + alr + 96) * K + (k0) + alc], rem);   \
        int rb0 = K - ((k0) + bkc); int rb1 = K - ((k0) + bkc + 16);           \
        pb0 = ldg4_tail(&Hm[(size_t)(n0 + bnr) * K + (k0) + bkc], rb0);        \
        pb1 = ldg4_tail(&Hm[(size_t)(n0 + bnr) * K + (k0) + bkc + 16], rb1);   \
    } while (0)

#define DIST_STORE() do {                                                      \
        As[alc + 0][alr] = pa0.x; As[alc + 1][alr] = pa0.y;                    \
        As[alc + 2][alr] = pa0.z; As[alc + 3][alr] = pa0.w;                    \
        As[alc + 0][alr + 32] = pa1.x; As[alc + 1][alr + 32] = pa1.y;          \
        As[alc + 2][alr + 32] = pa1.z; As[alc + 3][alr + 32] = pa1.w;          \
        As[alc + 0][alr + 64] = pa2.x; As[alc + 1][alr + 64] = pa2.y;          \
        As[alc + 2][alr + 64] = pa2.z; As[alc + 3][alr + 64] = pa2.w;          \
        As[alc + 0][alr + 96] = pa3.x; As[alc + 1][alr + 96] = pa3.y;          \
        As[alc + 2][alr + 96] = pa3.z; As[alc + 3][alr + 96] = pa3.w;          \
        Bs[bkc + 0][bnr] = pb0.x; Bs[bkc + 1][bnr] = pb0.y;                    \
        Bs[bkc + 2][bnr] = pb0.z; Bs[bkc + 3][bnr] = pb0.w;                    \
        Bs[bkc + 16][bnr] = pb1.x; Bs[bkc + 17][bnr] = pb1.y;                  \
        Bs[bkc + 18][bnr] = pb1.z; Bs[bkc + 19][bnr] = pb1.w;                  \
    } while (0)

    DIST_LOAD(0); DIST_STORE(); __syncthreads();
    for (int k0 = 0; k0 < K; k0 += 32) {
        bool more = (k0 + 32) < K;
        if (more) DIST_LOAD(k0 + 32);
        #pragma unroll
        for (int kk = 0; kk < 32; kk++) {
            float4 A0 = *(const float4*)&As[kk][ty * 8];
            float4 A1 = *(const float4*)&As[kk][ty * 8 + 4];
            float4 B0 = *(const float4*)&Bs[kk][tx * 4];
            float av[8] = {A0.x, A0.y, A0.z, A0.w, A1.x, A1.y, A1.z, A1.w};
            float bv[4] = {B0.x, B0.y, B0.z, B0.w};
            #pragma unroll
            for (int i = 0; i < 8; i++)
                #pragma unroll
                for (int j = 0; j < 4; j++) acc[i][j] = fmaf(av[i], bv[j], acc[i][j]);
        }
        __syncthreads();
        if (more) { DIST_STORE(); __syncthreads(); }
    }
#undef DIST_LOAD
#undef DIST_STORE

    float4 sqj = *(const float4*)&sq[n0 + tx * 4];
    float sqjv[4] = {sqj.x, sqj.y, sqj.z, sqj.w};
    #pragma unroll
    for (int ii = 0; ii < 8; ii++) {
        int i = m0 + ty * 8 + ii;
        float sqi = sq[i];
        int c0 = n0 + tx * 4;
        float dd[4];
        #pragma unroll
        for (int j = 0; j < 4; j++) {
            int col = c0 + j;
            float d2 = sqi + sqjv[j] - 2.0f * acc[ii][j];
            float d = sqrtf(fmaxf(d2, 0.f));
            dd[j] = d;
            if (col != i) {
                int bb = (int)ceilf((d - 1.7f) * 10.0f);
                bb = bb < 0 ? 0 : (bb > NBIN - 1 ? NBIN - 1 : bb);
                while (bb > 0 && d < tbl_s[bb - 1]) --bb;
                while (bb < NBIN - 1 && d >= tbl_s[bb]) ++bb;
                if (d < tbl_s[bb]) atomicAdd(&hist_s[bb], 1u);
            }
        }
        float4 dv; dv.x = dd[0]; dv.y = dd[1]; dv.z = dd[2]; dv.w = dd[3];
        *(float4*)&C[(size_t)i * N + c0] = dv;
    }
    __syncthreads();
    for (int idx = t; idx < NBIN; idx += 256)
        if (hist_s[idx]) atomicAdd(&hist_g[idx], hist_s[idx]);
}

// ---------------------------------------------------------------------------
// Parallel threshold pick: prefix-scan the NBIN-bin histogram, first cumulative
// count >= 615 (= first integer >= f32(0.3*2048)) selects tbl[k].
__global__ __launch_bounds__(256)
void k_pick(const unsigned* __restrict__ hist, const float* __restrict__ tbl,
            float* __restrict__ thrbuf) {
    __shared__ unsigned ps[256];
    __shared__ int sel;
    int t = threadIdx.x;
    if (t == 0) sel = NBIN - 1;
    unsigned v0 = hist[2 * t], v1 = hist[2 * t + 1];
    unsigned s = v0 + v1;
    ps[t] = s;
    __syncthreads();
    for (int o = 1; o < 256; o <<= 1) {
        unsigned add = (t >= o) ? ps[t - o] : 0u;
        __syncthreads();
        ps[t] += add;
        __syncthreads();
    }
    unsigned c = ps[t] - s;   // exclusive prefix
    int f = -1;
    c += v0; if (c >= 615u) f = 2 * t;
    else { c += v1; if (c >= 615u) f = 2 * t + 1; }
    if (f >= 0) atomicMin(&sel, f);
    __syncthreads();
    if (t == 0) thrbuf[0] = tbl[sel];
}

// ---------------------------------------------------------------------------
__global__ __launch_bounds__(256)
void k_deg(const float* __restrict__ dist, const float* __restrict__ thrbuf,
           float* __restrict__ dinv) {
    int t = threadIdx.x, lane = t & 63, wv = t >> 6;
    int row = blockIdx.x * 4 + wv;
    float thr = thrbuf[0];
    const float4* dr4 = (const float4*)&dist[(size_t)row * NN];
    int cnt = 0;
    #pragma unroll
    for (int bq = 0; bq < 8; bq++) {
        int i4 = bq * 64 + lane;
        float4 v = dr4[i4];
        int j = i4 * 4;
        cnt += (v.x < thr && j + 0 != row) ? 1 : 0;
        cnt += (v.y < thr && j + 1 != row) ? 1 : 0;
        cnt += (v.z < thr && j + 2 != row) ? 1 : 0;
        cnt += (v.w < thr && j + 3 != row) ? 1 : 0;
    }
    #pragma unroll
    for (int o = 32; o > 0; o >>= 1) cnt += __shfl_down(cnt, o, 64);
    if (lane == 0) dinv[row] = 1.0f / sqrtf((float)(cnt + 1));
}

// ---------------------------------------------------------------------------
// Per-row sparse GCN aggregate + bias + log_softmax. Block = one row.
// Deterministic neighbor compaction (scan-ordered, ascending j).
__global__ __launch_bounds__(256)
void k_gcn(const float* __restrict__ dist, const float* __restrict__ thrbuf,
           const float* __restrict__ dinv, const float* __restrict__ HW,
           const float* __restrict__ bias, float* __restrict__ outp) {
    __shared__ int nbr[2048];
    __shared__ float ndv[2048];
    __shared__ unsigned cnts[256];
    __shared__ float red[16];
    int t = threadIdx.x, lane = t & 63, wv = t >> 6;
    int i = blockIdx.x;
    float thr = thrbuf[0];
    const float* dr = &dist[(size_t)i * NN];
    float4 q0 = *(const float4*)&dr[t * 8];
    float4 q1 = *(const float4*)&dr[t * 8 + 4];
    float dv[8] = {q0.x, q0.y, q0.z, q0.w, q1.x, q1.y, q1.z, q1.w};
    unsigned lc = 0;
    #pragma unroll
    for (int q = 0; q < 8; q++) lc += (dv[q] < thr && (t * 8 + q) != i) ? 1u : 0u;
    cnts[t] = lc;
    __syncthreads();
    for (int o = 1; o < 256; o <<= 1) {
        unsigned add = (t >= o) ? cnts[t - o] : 0u;
        __syncthreads();
        cnts[t] += add;
        __syncthreads();
    }
    unsigned pos = cnts[t] - lc;
    int nn = (int)cnts[255];
    #pragma unroll
    for (int q = 0; q < 8; q++) {
        int j = t * 8 + q;
        if (dv[q] < thr && j != i) { nbr[pos] = j; ndv[pos] = dinv[j]; pos++; }
    }
    __syncthreads();
    float di = dinv[i];
    float v0, v1 = -1e30f, mx;
    {
        int d = t;
        float s = di * HW[(size_t)i * LL + d];
        for (int m = 0; m < nn; m++) s += ndv[m] * HW[(size_t)nbr[m] * LL + d];
        v0 = di * s + bias[d];
        mx = v0;
    }
    if (t + 256 < LL) {
        int d = t + 256;
        float s = di * HW[(size_t)i * LL + d];
        for (int m = 0; m < nn; m++) s += ndv[m] * HW[(size_t)nbr[m] * LL + d];
        v1 = di * s + bias[d];
        mx = fmaxf(mx, v1);
    }
    #pragma unroll
    for (int o = 32; o > 0; o >>= 1) mx = fmaxf(mx, __shfl_down(mx, o, 64));
    if (lane == 0) red[wv] = mx;
    __syncthreads();
    mx = fmaxf(fmaxf(red[0], red[1]), fmaxf(red[2], red[3]));
    float es = expf(v0 - mx) + ((t + 256 < LL) ? expf(v1 - mx) : 0.f);
    #pragma unroll
    for (int o = 32; o > 0; o >>= 1) es += __shfl_down(es, o, 64);
    if (lane == 0) red[8 + wv] = es;
    __syncthreads();
    float lse = logf(red[8] + red[9] + red[10] + red[11]);
    outp[(size_t)i * LL + t] = v0 - mx - lse;
    if (t + 256 < LL) outp[(size_t)i * LL + t + 256] = v1 - mx - lse;
}

// ---------------------------------------------------------------------------
extern "C" void kernel_launch(void* const* d_in, const int* in_sizes, int n_in,
                              void* d_out, int out_size, void* d_ws, size_t ws_size,
                              hipStream_t stream) {
    (void)in_sizes; (void)n_in; (void)out_size; (void)ws_size;
    const float* x   = (const float*)d_in[0];
    const float* c1w = (const float*)d_in[1];
    const float* c1b = (const float*)d_in[2];
    const float* c2w = (const float*)d_in[3];
    const float* c2b = (const float*)d_in[4];
    const float* fcw = (const float*)d_in[5];
    const float* fcb = (const float*)d_in[6];
    const float* gw  = (const float*)d_in[7];
    const float* gb  = (const float*)d_in[8];

    float* ws = (float*)d_ws;
    float* pool1 = ws + O_POOL1;
    float* pool2 = ws + O_POOL2;
    float* H     = ws + O_H;
    float* HWp   = ws + O_HW;
    float* distm = ws + O_DIST;
    float* sqv   = ws + O_SQ;
    float* tbl   = ws + O_TBL;
    unsigned* hist = (unsigned*)(ws + O_HIST);
    float* thr   = ws + O_THR;
    float* dinv  = ws + O_DINV;

    k_init<<<1, 256, 0, stream>>>(tbl, hist);
    k_conv1<<<512, 512, 0, stream>>>(x, c1w, c1b, pool1);
    k_conv2<<<512, 512, 0, stream>>>(pool1, c2w, c2b, pool2);
    k_gemm<1><<<dim3(16, 32), 256, 0, stream>>>(pool2, fcw, H, 2048, 500, 800, fcb);
    k_rowsq<<<512, 256, 0, stream>>>(H, sqv);
    k_dist<<<dim3(32, 16), 256, 0, stream>>>(H, distm, sqv, tbl, hist);
    k_pick<<<1, 256, 0, stream>>>(hist, tbl, thr);
    k_deg<<<512, 256, 0, stream>>>(distm, thr, dinv);
    k_gemm<0><<<dim3(16, 32), 256, 0, stream>>>(H, gw, HWp, 2048, 500, 500, nullptr);
    k_gcn<<<2048, 256, 0, stream>>>(distm, thr, dinv, HWp, gb, (float*)d_out);
}